// Round 5
// baseline (223.267 us; speedup 1.0000x reference)
//
#include <hip/hip_runtime.h>

// Problem constants (B=8, C=512, H=W=64, K=19 classes)
#define NCLS   19
#define NB     8
#define NC     512
#define NHW    4096      // 64*64
#define EPSM   1e-6f     // mean denominator eps
#define EPSC   1e-8f     // cosine eps

// Workspace layout (bytes)
#define OFF_LABELS   0u          // int32 [NB*NHW]
#define OFF_COUNTS   131072u     // float [NB*NCLS] (zeroed each launch, atomic)
#define OFF_SUMS_S0  132096u     // float [NB][NCLS][NC] partial half 0 (becomes means)
#define OFF_SUMS_S1  443392u     // float [NB][NCLS][NC] partial half 1
#define OFF_SUMS_T0  754688u
#define OFF_SUMS_T1  1065984u
#define OFF_NORM_S   1377280u
#define OFF_NORM_T   1378304u
#define OFF_PART     1379328u    // float [4 arrays][8 chunks][NB*NHW] = 4 MB
// total ~5.4 MB

// ---------------------------------------------------------------------------
// Wave-64 sum via DPP (VALU pipe only, no LDS). Result valid in lane 63.
template<int CTRL>
__device__ __forceinline__ float dpp_add(float x) {
    int y = __builtin_amdgcn_update_dpp(0, __float_as_int(x), CTRL, 0xf, 0xf, false);
    return x + __int_as_float(y);
}
__device__ __forceinline__ float wave64_sum(float x) {
    x = dpp_add<0x111>(x);   // row_shr:1
    x = dpp_add<0x112>(x);   // row_shr:2
    x = dpp_add<0x114>(x);   // row_shr:4
    x = dpp_add<0x118>(x);   // row_shr:8
    x = dpp_add<0x142>(x);   // row_bcast:15
    x = dpp_add<0x143>(x);   // row_bcast:31 -> lane63 has total
    return x;
}

// ---------------------------------------------------------------------------
// Kernel 1: nearest-resize labels + per-batch class counts.
// 64 blocks (8 per batch) for wave-parallelism; counts via global float
// atomicAdd (integer-valued floats: exact, order-independent).
__global__ __launch_bounds__(256) void k_labels(const int* __restrict__ target,
                                                int* __restrict__ labels,
                                                float* __restrict__ counts) {
    __shared__ int hist[NCLS];
    const int blk = blockIdx.x;
    const int b = blk >> 3, seg = blk & 7;
    const int t = threadIdx.x;
    if (t < NCLS) hist[t] = 0;
    __syncthreads();
    const int* tb = target + (size_t)b * 512 * 512;
    #pragma unroll
    for (int i = 0; i < 2; ++i) {
        int n = seg * 512 + t + i * 256;
        int y = n >> 6, x = n & 63;
        int l = tb[(y * 8) * 512 + x * 8];   // in_idx = floor(out_idx*512/64)
        labels[b * NHW + n] = l;
        if (l >= 0 && l < NCLS) atomicAdd(&hist[l], 1);
    }
    __syncthreads();
    if (t < NCLS) atomicAdd(&counts[b * NCLS + t], (float)hist[t]);
}

// ---------------------------------------------------------------------------
// Kernel 2: per-class channel sums, register-resident compare-select.
// Each WAVE owns 2 channels of ONE tensor and HALF the pixels (2048):
// 38 accumulators/thread (VGPR ~75 -> 6 waves/SIMD resident).
// Grid: 2048 blocks = 8192 waves = 8 b x 256 cpair x 2 tensor x 2 half.
// NOTE launch_bounds 2nd arg: compiler caps VGPR at ~256/w (r3: w=4 -> 64
// VGPR -> total spill). w=2 -> cap 128, body needs ~75. Do not raise.
__global__ __launch_bounds__(256, 2) void k_sums(const float* __restrict__ fS,
                                                 const float* __restrict__ fT,
                                                 const int* __restrict__ labels,
                                                 float* __restrict__ psS0,
                                                 float* __restrict__ psS1,
                                                 float* __restrict__ psT0,
                                                 float* __restrict__ psT1) {
    const int t = threadIdx.x;
    const int lane = t & 63;
    const int u = (blockIdx.x << 2) + (t >> 6);   // wave-unit 0..8191
    const int b = u >> 10;
    const int rem = u & 1023;
    const int c0 = (rem >> 2) << 1;               // channel pair c0, c0+1
    const int tensor = (rem >> 1) & 1;            // 0 = S, 1 = T
    const int half = rem & 1;                     // pixel half
    const size_t base = ((size_t)(b * NC) + c0) * NHW;
    const float* f = tensor ? fT : fS;
    const float4* p0 = (const float4*)(f + base);
    const float4* p1 = (const float4*)(f + base + NHW);
    const int4* lab4 = (const int4*)(labels + b * NHW);
    const int poff = half << 9;                   // float4 offset: 512 per half

    float a0[NCLS], a1[NCLS];
    #pragma unroll
    for (int k = 0; k < NCLS; ++k) { a0[k] = a1[k] = 0.f; }

    #pragma unroll 2
    for (int i = 0; i < 8; ++i) {
        const int idx = poff + lane + (i << 6);   // float4 index (4 pixels)
        const float4 v0 = p0[idx];
        const float4 v1 = p1[idx];
        const int4 l4 = lab4[idx];
        #pragma unroll
        for (int k = 0; k < NCLS; ++k) {
            const float m0 = (l4.x == k) ? 1.f : 0.f;
            const float m1 = (l4.y == k) ? 1.f : 0.f;
            const float m2 = (l4.z == k) ? 1.f : 0.f;
            const float m3 = (l4.w == k) ? 1.f : 0.f;
            a0[k] += m0 * v0.x + m1 * v0.y + m2 * v0.z + m3 * v0.w;
            a1[k] += m0 * v1.x + m1 * v1.y + m2 * v1.z + m3 * v1.w;
        }
    }
    #pragma unroll
    for (int k = 0; k < NCLS; ++k) {
        a0[k] = wave64_sum(a0[k]);
        a1[k] = wave64_sum(a1[k]);
    }
    if (lane == 63) {
        float* dst = tensor ? (half ? psT1 : psT0) : (half ? psS1 : psS0);
        #pragma unroll
        for (int k = 0; k < NCLS; ++k) {
            *(float2*)(dst + ((size_t)(b * NCLS + k)) * NC + c0) = make_float2(a0[k], a1[k]);
        }
    }
}

// ---------------------------------------------------------------------------
// Kernel 3: combine partial halves, means = sum/(count+eps) (into psS0/psT0),
// plus per-(b,k) center norms. One wave per (b,k); coalesced.
__global__ __launch_bounds__(64) void k_means(float* __restrict__ psS0,
                                              const float* __restrict__ psS1,
                                              float* __restrict__ psT0,
                                              const float* __restrict__ psT1,
                                              const float* __restrict__ counts,
                                              float* __restrict__ normS,
                                              float* __restrict__ normT) {
    const int bk = blockIdx.x;
    const int t = threadIdx.x;
    const float inv = 1.f / (counts[bk] + EPSM);
    const size_t row = (size_t)bk * NC;
    float aS = 0.f, aT = 0.f;
    #pragma unroll
    for (int i = 0; i < NC / 64; ++i) {
        const int c = t + i * 64;
        float mS = (psS0[row + c] + psS1[row + c]) * inv;
        float mT = (psT0[row + c] + psT1[row + c]) * inv;
        psS0[row + c] = mS; aS += mS * mS;
        psT0[row + c] = mT; aT += mT * mT;
    }
    aS = wave64_sum(aS);
    aT = wave64_sum(aT);
    if (t == 63) { normS[bk] = sqrtf(aS); normT[bk] = sqrtf(aT); }
}

// ---------------------------------------------------------------------------
// Kernel 4: per-pixel dot(f, mean[lab]) and ||f||^2, atomic-free.
// Each thread owns 2 adjacent pixels (float2 loads, 8B); 128-thread blocks.
// Grid: 8 b x 16 pixel-tiles(256 px) x 8 c-chunks = 1024 blocks.
// Means tile in LDS stride 65 -> gather bank = (lc+ci)%32, conflict-free.
#define CCH 64
__global__ __launch_bounds__(128) void k_dots(const float* __restrict__ fS,
                                              const float* __restrict__ fT,
                                              const float* __restrict__ meansS,
                                              const float* __restrict__ meansT,
                                              const int* __restrict__ labels,
                                              float* __restrict__ part) {
    __shared__ float mS[NCLS * 65];
    __shared__ float mT[NCLS * 65];
    const int blk = blockIdx.x;
    const int chunk = blk & 7;
    const int tile  = (blk >> 3) & 15;
    const int b     = blk >> 7;
    const int t = threadIdx.x;
    const int c0 = chunk * CCH;
    const int n0 = tile * 256 + t * 2;            // two adjacent pixels

    for (int i = t; i < NCLS * CCH; i += 128) {
        const int k = i >> 6, j = i & 63;
        mS[k * 65 + j] = meansS[((size_t)(b * NCLS + k)) * NC + c0 + j];
        mT[k * 65 + j] = meansT[((size_t)(b * NCLS + k)) * NC + c0 + j];
    }
    __syncthreads();

    const int2 l2 = *(const int2*)(labels + b * NHW + n0);
    const int lca = (l2.x >= 0 && l2.x < NCLS) ? l2.x : 0;
    const int lcb = (l2.y >= 0 && l2.y < NCLS) ? l2.y : 0;
    const float* pS = fS + ((size_t)(b * NC + c0)) * NHW + n0;
    const float* pT = fT + ((size_t)(b * NC + c0)) * NHW + n0;
    float dSa = 0.f, dSb = 0.f, nSa = 0.f, nSb = 0.f;
    float dTa = 0.f, dTb = 0.f, nTa = 0.f, nTb = 0.f;
    #pragma unroll 16
    for (int ci = 0; ci < CCH; ++ci) {
        const float2 vS = *(const float2*)(pS + (size_t)ci * NHW);
        const float2 vT = *(const float2*)(pT + (size_t)ci * NHW);
        const float msa = mS[lca * 65 + ci];
        const float msb = mS[lcb * 65 + ci];
        const float mta = mT[lca * 65 + ci];
        const float mtb = mT[lcb * 65 + ci];
        dSa += vS.x * msa; nSa += vS.x * vS.x;
        dSb += vS.y * msb; nSb += vS.y * vS.y;
        dTa += vT.x * mta; nTa += vT.x * vT.x;
        dTb += vT.y * mtb; nTb += vT.y * vT.y;
    }
    const size_t p0 = (size_t)b * NHW + n0;
    *(float2*)(part + ((size_t)(0 * 8 + chunk)) * (NB * NHW) + p0) = make_float2(dSa, dSb);
    *(float2*)(part + ((size_t)(1 * 8 + chunk)) * (NB * NHW) + p0) = make_float2(nSa, nSb);
    *(float2*)(part + ((size_t)(2 * 8 + chunk)) * (NB * NHW) + p0) = make_float2(dTa, dTb);
    *(float2*)(part + ((size_t)(3 * 8 + chunk)) * (NB * NHW) + p0) = make_float2(nTa, nTb);
}

// ---------------------------------------------------------------------------
// Kernel 5: combine partials, cosines, MSE reduce.
__global__ __launch_bounds__(256) void k_final(const float* __restrict__ part,
                                               const int* __restrict__ labels,
                                               const float* __restrict__ normS,
                                               const float* __restrict__ normT,
                                               float* __restrict__ out) {
    __shared__ float red[4];
    const int p = blockIdx.x * 256 + threadIdx.x;
    const int b = p >> 12;
    float dS = 0.f, nS = 0.f, dT = 0.f, nT = 0.f;
    #pragma unroll
    for (int ch = 0; ch < 8; ++ch) {
        dS += part[((size_t)(0 * 8 + ch)) * (NB * NHW) + p];
        nS += part[((size_t)(1 * 8 + ch)) * (NB * NHW) + p];
        dT += part[((size_t)(2 * 8 + ch)) * (NB * NHW) + p];
        nT += part[((size_t)(3 * 8 + ch)) * (NB * NHW) + p];
    }
    const int l = labels[p];
    float val = 0.f;
    if (l >= 0 && l < NCLS) {
        float cS = dS / (fmaxf(sqrtf(nS), EPSC) * fmaxf(normS[b * NCLS + l], EPSC));
        float cT = dT / (fmaxf(sqrtf(nT), EPSC) * fmaxf(normT[b * NCLS + l], EPSC));
        float d = cS - cT;
        val = d * d;
    }
    val = wave64_sum(val);
    if ((threadIdx.x & 63) == 63) red[threadIdx.x >> 6] = val;
    __syncthreads();
    if (threadIdx.x == 0)
        atomicAdd(out, (red[0] + red[1] + red[2] + red[3]) * (1.f / (NB * NHW)));
}

// ---------------------------------------------------------------------------
extern "C" void kernel_launch(void* const* d_in, const int* in_sizes, int n_in,
                              void* d_out, int out_size, void* d_ws, size_t ws_size,
                              hipStream_t stream) {
    (void)in_sizes; (void)n_in; (void)out_size; (void)ws_size;
    const float* fS     = (const float*)d_in[0];
    const float* fT     = (const float*)d_in[1];
    const int*   target = (const int*)d_in[2];

    char* ws = (char*)d_ws;
    int*   labels = (int*)  (ws + OFF_LABELS);
    float* counts = (float*)(ws + OFF_COUNTS);
    float* psS0   = (float*)(ws + OFF_SUMS_S0);   // becomes meansS
    float* psS1   = (float*)(ws + OFF_SUMS_S1);
    float* psT0   = (float*)(ws + OFF_SUMS_T0);   // becomes meansT
    float* psT1   = (float*)(ws + OFF_SUMS_T1);
    float* normS  = (float*)(ws + OFF_NORM_S);
    float* normT  = (float*)(ws + OFF_NORM_T);
    float* part   = (float*)(ws + OFF_PART);

    hipMemsetAsync(d_out, 0, sizeof(float), stream);
    hipMemsetAsync(counts, 0, 1024, stream);

    k_labels<<<NB * 8, 256, 0, stream>>>(target, labels, counts);
    k_sums  <<<NB * NC / 2, 256, 0, stream>>>(fS, fT, labels, psS0, psS1, psT0, psT1);
    k_means <<<NB * NCLS, 64, 0, stream>>>(psS0, psS1, psT0, psT1, counts, normS, normT);
    k_dots  <<<NB * 16 * 8, 128, 0, stream>>>(fS, fT, psS0, psT0, labels, part);
    k_final <<<NB * NHW / 256, 256, 0, stream>>>(part, labels, normS, normT,
                                                 (float*)d_out);
}